// Round 1
// baseline (115.556 us; speedup 1.0000x reference)
//
#include <hip/hip_runtime.h>

#define BATCH     4096
#define NCTX      8
#define NK        6
#define VDIM      256
#define NWORDS    50000

__global__ __launch_bounds__(256)
void DM_42417097016803_kernel(const int* __restrict__ ctx,
                              const int* __restrict__ doc,
                              const int* __restrict__ tid,
                              const float* __restrict__ D,
                              const float* __restrict__ W,
                              const float* __restrict__ O,
                              float* __restrict__ out)
{
    const int b = blockIdx.x;       // batch element
    const int t = threadIdx.x;      // 0..255 == vector dim d

    __shared__ int s_idx[NCTX + NK + 1];
    if (t < NCTX)            s_idx[t] = ctx[b * NCTX + t];
    else if (t < NCTX + NK)  s_idx[t] = tid[b * NK + (t - NCTX)];
    else if (t == NCTX + NK) s_idx[t] = doc[b];
    __syncthreads();

    // x[b, t] = D[doc, t] + sum_c W[ctx_c, t]   (coalesced row loads)
    const int docid = s_idx[NCTX + NK];
    float x = D[(size_t)docid * VDIM + t];
#pragma unroll
    for (int c = 0; c < NCTX; ++c)
        x += W[(size_t)s_idx[c] * VDIM + t];

    // p[k] = x * O[t, tid_k]  (strided gather, 6 independent loads in flight)
    float p[NK];
#pragma unroll
    for (int k = 0; k < NK; ++k)
        p[k] = x * O[(size_t)t * NWORDS + s_idx[NCTX + k]];

    // reduce over 256 threads: butterfly within wave64, then LDS across 4 waves
#pragma unroll
    for (int k = 0; k < NK; ++k) {
#pragma unroll
        for (int off = 32; off >= 1; off >>= 1)
            p[k] += __shfl_down(p[k], off, 64);
    }

    __shared__ float s_part[4][NK];
    const int wave = t >> 6;
    const int lane = t & 63;
    if (lane == 0) {
#pragma unroll
        for (int k = 0; k < NK; ++k) s_part[wave][k] = p[k];
    }
    __syncthreads();

    if (t < NK) {
        out[b * NK + t] = s_part[0][t] + s_part[1][t] + s_part[2][t] + s_part[3][t];
    }
}

extern "C" void kernel_launch(void* const* d_in, const int* in_sizes, int n_in,
                              void* d_out, int out_size, void* d_ws, size_t ws_size,
                              hipStream_t stream)
{
    const int*   ctx = (const int*)d_in[0];   // (4096, 8)
    const int*   doc = (const int*)d_in[1];   // (4096,)
    const int*   tid = (const int*)d_in[2];   // (4096, 6)
    const float* D   = (const float*)d_in[3]; // (100000, 256)
    const float* W   = (const float*)d_in[4]; // (50000, 256)
    const float* O   = (const float*)d_in[5]; // (256, 50000)
    float*       out = (float*)d_out;         // (4096, 6)

    DM_42417097016803_kernel<<<BATCH, 256, 0, stream>>>(ctx, doc, tid, D, W, O, out);
}

// Round 2
// 33.420 us; speedup vs baseline: 3.4577x; 3.4577x over previous
//
#include <hip/hip_runtime.h>

#define BATCH     4096
#define NCTX      8
#define NK        6
#define VDIM      256
#define NWORDS    50000

// ---------------------------------------------------------------------------
// Kernel 1: transpose O (256 x 50000, row-major) -> OT (50000 x 256) in d_ws.
// 64x64 tiles, 256 threads, float4 global loads + float4 global stores.
// ---------------------------------------------------------------------------
__global__ __launch_bounds__(256)
void DM_42417097016803_transpose(const float* __restrict__ O,
                                 float* __restrict__ OT)
{
    __shared__ float lds[64][65];   // +1 pad: LDS reads below are ~2-way (free)

    const int tid     = threadIdx.x;
    const int colBase = blockIdx.x * 64;   // word index
    const int rowBase = blockIdx.y * 64;   // dim index (256/64 = 4 tiles)

    // Load: 64 rows x 16 float4 per tile = 1024 float4; 4 per thread.
#pragma unroll
    for (int i = 0; i < 4; ++i) {
        const int idx = tid + i * 256;
        const int r   = idx >> 4;          // 0..63
        const int c4  = idx & 15;          // 0..15
        const int col = colBase + c4 * 4;
        if (col < NWORDS) {                // NWORDS % 4 == 0: whole float4 valid
            const float4 v = *reinterpret_cast<const float4*>(
                &O[(size_t)(rowBase + r) * NWORDS + col]);
            lds[r][c4 * 4 + 0] = v.x;
            lds[r][c4 * 4 + 1] = v.y;
            lds[r][c4 * 4 + 2] = v.z;
            lds[r][c4 * 4 + 3] = v.w;
        }
    }
    __syncthreads();

    // Store: OT[col][rowBase + r] contiguous along r -> float4 stores.
#pragma unroll
    for (int i = 0; i < 4; ++i) {
        const int idx = tid + i * 256;
        const int c   = idx >> 4;          // 0..63 (word within tile)
        const int r4  = idx & 15;          // 0..15 (float4 within dim-64)
        const int col = colBase + c;
        if (col < NWORDS) {
            float4 v;
            v.x = lds[r4 * 4 + 0][c];
            v.y = lds[r4 * 4 + 1][c];
            v.z = lds[r4 * 4 + 2][c];
            v.w = lds[r4 * 4 + 3][c];
            *reinterpret_cast<float4*>(
                &OT[(size_t)col * VDIM + rowBase + r4 * 4]) = v;
        }
    }
}

// ---------------------------------------------------------------------------
// Kernel 2: one wave per batch element; float4 per lane (lane l owns dims
// 4l..4l+3). All global loads are coalesced 16 B/lane. Wave-local reduction.
// ---------------------------------------------------------------------------
__global__ __launch_bounds__(256)
void DM_42417097016803_score(const int* __restrict__ ctx,
                             const int* __restrict__ doc,
                             const int* __restrict__ tid,
                             const float* __restrict__ D,
                             const float* __restrict__ W,
                             const float* __restrict__ OT,
                             float* __restrict__ out)
{
    const int wave = threadIdx.x >> 6;
    const int lane = threadIdx.x & 63;
    const int b    = blockIdx.x * 4 + wave;

    const float4* __restrict__ D4  = reinterpret_cast<const float4*>(D);
    const float4* __restrict__ W4  = reinterpret_cast<const float4*>(W);
    const float4* __restrict__ OT4 = reinterpret_cast<const float4*>(OT);

    // x[4] = D[doc] + sum_c W[ctx_c]   (rows are 64 float4 wide)
    const int docid = doc[b];
    float4 x = D4[(size_t)docid * 64 + lane];
#pragma unroll
    for (int c = 0; c < NCTX; ++c) {
        const int id = ctx[b * NCTX + c];
        const float4 w = W4[(size_t)id * 64 + lane];
        x.x += w.x; x.y += w.y; x.z += w.z; x.w += w.w;
    }

    // p[k] = dot(x, OT[id_k])  over this lane's 4 dims
    float p[NK];
#pragma unroll
    for (int k = 0; k < NK; ++k) {
        const int id = tid[b * NK + k];
        const float4 o = OT4[(size_t)id * 64 + lane];
        p[k] = x.x * o.x + x.y * o.y + x.z * o.z + x.w * o.w;
    }

    // wave64 butterfly reduction
#pragma unroll
    for (int k = 0; k < NK; ++k) {
#pragma unroll
        for (int off = 32; off >= 1; off >>= 1)
            p[k] += __shfl_down(p[k], off, 64);
    }

    if (lane == 0) {
#pragma unroll
        for (int k = 0; k < NK; ++k)
            out[b * NK + k] = p[k];
    }
}

// ---------------------------------------------------------------------------
// Fallback (direct strided-O gather) in case ws_size < |O^T|.
// ---------------------------------------------------------------------------
__global__ __launch_bounds__(256)
void DM_42417097016803_fallback(const int* __restrict__ ctx,
                                const int* __restrict__ doc,
                                const int* __restrict__ tid,
                                const float* __restrict__ D,
                                const float* __restrict__ W,
                                const float* __restrict__ O,
                                float* __restrict__ out)
{
    const int b = blockIdx.x;
    const int t = threadIdx.x;

    __shared__ int s_idx[NCTX + NK + 1];
    if (t < NCTX)            s_idx[t] = ctx[b * NCTX + t];
    else if (t < NCTX + NK)  s_idx[t] = tid[b * NK + (t - NCTX)];
    else if (t == NCTX + NK) s_idx[t] = doc[b];
    __syncthreads();

    const int docid = s_idx[NCTX + NK];
    float x = D[(size_t)docid * VDIM + t];
#pragma unroll
    for (int c = 0; c < NCTX; ++c)
        x += W[(size_t)s_idx[c] * VDIM + t];

    float p[NK];
#pragma unroll
    for (int k = 0; k < NK; ++k)
        p[k] = x * O[(size_t)t * NWORDS + s_idx[NCTX + k]];

#pragma unroll
    for (int k = 0; k < NK; ++k) {
#pragma unroll
        for (int off = 32; off >= 1; off >>= 1)
            p[k] += __shfl_down(p[k], off, 64);
    }

    __shared__ float s_part[4][NK];
    const int wave = t >> 6;
    const int lane = t & 63;
    if (lane == 0) {
#pragma unroll
        for (int k = 0; k < NK; ++k) s_part[wave][k] = p[k];
    }
    __syncthreads();

    if (t < NK)
        out[b * NK + t] = s_part[0][t] + s_part[1][t] + s_part[2][t] + s_part[3][t];
}

extern "C" void kernel_launch(void* const* d_in, const int* in_sizes, int n_in,
                              void* d_out, int out_size, void* d_ws, size_t ws_size,
                              hipStream_t stream)
{
    const int*   ctx = (const int*)d_in[0];   // (4096, 8)
    const int*   doc = (const int*)d_in[1];   // (4096,)
    const int*   tid = (const int*)d_in[2];   // (4096, 6)
    const float* D   = (const float*)d_in[3]; // (100000, 256)
    const float* W   = (const float*)d_in[4]; // (50000, 256)
    const float* O   = (const float*)d_in[5]; // (256, 50000)
    float*       out = (float*)d_out;         // (4096, 6)

    const size_t ot_bytes = (size_t)NWORDS * VDIM * sizeof(float); // 51.2 MB

    if (ws_size >= ot_bytes) {
        float* OT = (float*)d_ws;
        dim3 tgrid((NWORDS + 63) / 64, VDIM / 64);
        DM_42417097016803_transpose<<<tgrid, 256, 0, stream>>>(O, OT);
        DM_42417097016803_score<<<BATCH / 4, 256, 0, stream>>>(
            ctx, doc, tid, D, W, OT, out);
    } else {
        DM_42417097016803_fallback<<<BATCH, 256, 0, stream>>>(
            ctx, doc, tid, D, W, O, out);
    }
}